// Round 4
// baseline (142.346 us; speedup 1.0000x reference)
//
#include <hip/hip_runtime.h>
#include <hip/hip_bf16.h>
#include <hip/hip_cooperative_groups.h>

namespace cg = cooperative_groups;

constexpr int B = 8, K = 256, F = 64, E = 128;   // E = 2*F

// ---------------------------------------------------------------------------
// Single cooperative kernel, 512 blocks x 256 threads, 3 phases:
//  P0: pack lin_w -> wq (coalesced main-loop reads), fc_w -> fcp
//  A : u[bk][e], vT (float4-transposed), c[bk]=sum a*v, d[bk]=sum a*u
//  B : e_ij = 0.6(d_i+c_j) + sum(0.4a)|u+v| + bias -> softmax -> h -> fc
// Workspace floats: u 262144 | vT 262144 | c 2048 | d 2048 | wq 16384 | fcp 4096
// ---------------------------------------------------------------------------
__global__ __launch_bounds__(256, 2) void gat_fused(
    const float* __restrict__ x, const float* __restrict__ lin_w,
    const float* __restrict__ lin_b, const float* __restrict__ a,
    const float* __restrict__ att_bias, const float* __restrict__ fc_w,
    const float* __restrict__ fc_b, float* __restrict__ u,
    float* __restrict__ vT, float* __restrict__ c, float* __restrict__ d,
    float4* __restrict__ wq, float4* __restrict__ fcp,
    float* __restrict__ out)
{
    cg::grid_group gg = cg::this_grid();
    const int blk = blockIdx.x;          // 0..511
    const int t = threadIdx.x;           // 0..255
    const int wave = t >> 6, lane = t & 63;
    const int b = blk >> 6;
    const int i0 = (blk & 63) * 4;

    __shared__ float xs[4 * F];
    __shared__ float redA[4][4];
    __shared__ float us[4 * E];
    __shared__ float aas[E];
    __shared__ float ps[4 * 257];
    __shared__ float4 hpart[4][4][16];
    __shared__ float4 h4s[4][16];
    __shared__ float redm[4][4], reds[4][4];

    // ---------------- phase 0: weight packing (first 20 blocks) ----------------
    {
        int idx = blk * 256 + t;
        if (idx < 32 * E) {                       // lin_w -> wq
            int e = idx & (E - 1), f2 = idx >> 7;
            const float* r = lin_w + e * (2 * F) + 2 * f2;
            wq[f2 * E + e] = make_float4(r[0], r[1], r[F], r[F + 1]);
        } else if (idx < 32 * E + 1024) {         // fc_w -> fcp
            int kk = idx - 32 * E;
            int f4 = kk >> 6, o = kk & 63;
            const float* r = fc_w + o * F + f4 * 4;
            fcp[kk] = make_float4(r[0], r[1], r[2], r[3]);
        }
    }
    gg.sync();

    // ---------------- phase A: u, vT, c, d (2 rows per thread) ----------------
    {
        const int row0 = blk * 4;
        const int e = t & 127, rh = t >> 7;
        xs[t] = x[row0 * F + t];
        __syncthreads();
        const float* xr0 = &xs[(rh * 2) * F];
        const float* xr1 = &xs[(rh * 2 + 1) * F];
        float a10 = 0.f, a11 = 0.f, a20 = 0.f, a21 = 0.f;
#pragma unroll
        for (int f2 = 0; f2 < 32; ++f2) {
            float4 w = wq[f2 * E + e];           // coalesced 16B/lane
            float x0 = xr0[2 * f2], x1 = xr0[2 * f2 + 1];
            float y0 = xr1[2 * f2], y1 = xr1[2 * f2 + 1];
            a10 = fmaf(w.x, x0, fmaf(w.y, x1, a10));
            a20 = fmaf(w.z, x0, fmaf(w.w, x1, a20));
            a11 = fmaf(w.x, y0, fmaf(w.y, y1, a11));
            a21 = fmaf(w.z, y0, fmaf(w.w, y1, a21));
        }
        const float bb = lin_b[e], av = a[e];
        const float u0 = a10 + bb, u1 = a11 + bb;
        const int r0 = row0 + rh * 2;
        u[r0 * E + e] = u0;
        u[(r0 + 1) * E + e] = u1;
        const int kk = (blk & 63) * 4 + rh * 2;
        float* vbase = vT + ((b * 32 + (e >> 2)) * K) * 4 + (e & 3);
        vbase[kk * 4] = a20;
        vbase[(kk + 1) * 4] = a21;
        float vals[4] = {av * a20, av * u0, av * a21, av * u1};  // c0,d0,c1,d1
#pragma unroll
        for (int off = 32; off; off >>= 1) {
#pragma unroll
            for (int q = 0; q < 4; ++q) vals[q] += __shfl_xor(vals[q], off);
        }
        if (lane == 0) {
            redA[wave][0] = vals[0]; redA[wave][1] = vals[1];
            redA[wave][2] = vals[2]; redA[wave][3] = vals[3];
        }
        if (t < E) aas[t] = 0.4f * a[t];
        __syncthreads();
        if (t < 8) {
            int r = t >> 1, w = t & 1;           // row 0..3, 0=c 1=d
            int wp = (r >> 1) * 2, q = (r & 1) * 2 + w;
            float val = redA[wp][q] + redA[wp + 1][q];
            if (w == 0) c[row0 + r] = val; else d[row0 + r] = val;
        }
    }
    // hoist att_bias (pure input) — latency hides under the grid barrier
    const float ab0 = att_bias[(i0 + 0) * K + t];
    const float ab1 = att_bias[(i0 + 1) * K + t];
    const float ab2 = att_bias[(i0 + 2) * K + t];
    const float ab3 = att_bias[(i0 + 3) * K + t];
    gg.sync();

    // ---------------- phase B: attention + h + fc ----------------
    {
        const float* usrc = u + (size_t)(b * K + i0) * E;
        us[t]       = usrc[t];
        us[t + 256] = usrc[t + 256];
        const float cj = c[b * K + t];
        const float d0 = d[b * K + i0],     d1 = d[b * K + i0 + 1];
        const float d2 = d[b * K + i0 + 2], d3 = d[b * K + i0 + 3];
        __syncthreads();

        // e-loop: 2 VALU/elem (add + fma with |.| modifier), 1 global load/iter
        const float4* v4 = (const float4*)vT + (size_t)b * 32 * K + t;
        float ej0 = 0.f, ej1 = 0.f, ej2 = 0.f, ej3 = 0.f;
#pragma unroll 8
        for (int e4 = 0; e4 < 32; ++e4) {
            float4 v  = v4[e4 * K];
            float4 aa = *(const float4*)&aas[e4 * 4];
            float4 u0 = *(const float4*)&us[0 * E + e4 * 4];
            float4 u1 = *(const float4*)&us[1 * E + e4 * 4];
            float4 u2 = *(const float4*)&us[2 * E + e4 * 4];
            float4 u3 = *(const float4*)&us[3 * E + e4 * 4];
            ej0 = fmaf(aa.x, fabsf(u0.x + v.x), ej0); ej0 = fmaf(aa.y, fabsf(u0.y + v.y), ej0);
            ej0 = fmaf(aa.z, fabsf(u0.z + v.z), ej0); ej0 = fmaf(aa.w, fabsf(u0.w + v.w), ej0);
            ej1 = fmaf(aa.x, fabsf(u1.x + v.x), ej1); ej1 = fmaf(aa.y, fabsf(u1.y + v.y), ej1);
            ej1 = fmaf(aa.z, fabsf(u1.z + v.z), ej1); ej1 = fmaf(aa.w, fabsf(u1.w + v.w), ej1);
            ej2 = fmaf(aa.x, fabsf(u2.x + v.x), ej2); ej2 = fmaf(aa.y, fabsf(u2.y + v.y), ej2);
            ej2 = fmaf(aa.z, fabsf(u2.z + v.z), ej2); ej2 = fmaf(aa.w, fabsf(u2.w + v.w), ej2);
            ej3 = fmaf(aa.x, fabsf(u3.x + v.x), ej3); ej3 = fmaf(aa.y, fabsf(u3.y + v.y), ej3);
            ej3 = fmaf(aa.z, fabsf(u3.z + v.z), ej3); ej3 = fmaf(aa.w, fabsf(u3.w + v.w), ej3);
        }
        float e0 = fmaf(0.6f, d0 + cj, ej0) + ab0;
        float e1 = fmaf(0.6f, d1 + cj, ej1) + ab1;
        float e2 = fmaf(0.6f, d2 + cj, ej2) + ab2;
        float e3 = fmaf(0.6f, d3 + cj, ej3) + ab3;

        // softmax over j (4 rows)
        float m0 = e0, m1 = e1, m2 = e2, m3 = e3;
#pragma unroll
        for (int off = 32; off; off >>= 1) {
            m0 = fmaxf(m0, __shfl_xor(m0, off)); m1 = fmaxf(m1, __shfl_xor(m1, off));
            m2 = fmaxf(m2, __shfl_xor(m2, off)); m3 = fmaxf(m3, __shfl_xor(m3, off));
        }
        if (lane == 0) { redm[wave][0] = m0; redm[wave][1] = m1; redm[wave][2] = m2; redm[wave][3] = m3; }
        __syncthreads();
        m0 = fmaxf(fmaxf(redm[0][0], redm[1][0]), fmaxf(redm[2][0], redm[3][0]));
        m1 = fmaxf(fmaxf(redm[0][1], redm[1][1]), fmaxf(redm[2][1], redm[3][1]));
        m2 = fmaxf(fmaxf(redm[0][2], redm[1][2]), fmaxf(redm[2][2], redm[3][2]));
        m3 = fmaxf(fmaxf(redm[0][3], redm[1][3]), fmaxf(redm[2][3], redm[3][3]));
        float x0 = __expf(e0 - m0), x1 = __expf(e1 - m1), x2 = __expf(e2 - m2), x3 = __expf(e3 - m3);
        float s0 = x0, s1 = x1, s2 = x2, s3 = x3;
#pragma unroll
        for (int off = 32; off; off >>= 1) {
            s0 += __shfl_xor(s0, off); s1 += __shfl_xor(s1, off);
            s2 += __shfl_xor(s2, off); s3 += __shfl_xor(s3, off);
        }
        if (lane == 0) { reds[wave][0] = s0; reds[wave][1] = s1; reds[wave][2] = s2; reds[wave][3] = s3; }
        __syncthreads();
        s0 = reds[0][0] + reds[1][0] + reds[2][0] + reds[3][0];
        s1 = reds[0][1] + reds[1][1] + reds[2][1] + reds[3][1];
        s2 = reds[0][2] + reds[1][2] + reds[2][2] + reds[3][2];
        s3 = reds[0][3] + reds[1][3] + reds[2][3] + reds[3][3];
        ps[0 * 257 + t] = x0 / s0;
        ps[1 * 257 + t] = x1 / s1;
        ps[2 * 257 + t] = x2 / s2;
        ps[3 * 257 + t] = x3 / s3;
        __syncthreads();

        // h-loop: thread = (jg, fq); each x value loaded ONCE, feeds 4 i-rows
        {
            const int jg = t >> 4, fq = t & 15;
            const float4* xb4 = (const float4*)x + (size_t)b * K * 16 + fq;
            float4 h0 = make_float4(0,0,0,0), h1 = h0, h2 = h0, h3 = h0;
#pragma unroll 4
            for (int jj = 0; jj < 16; ++jj) {
                int j = jg * 16 + jj;
                float4 xv = xb4[(size_t)j * 16];
                float p0 = ps[0 * 257 + j], p1 = ps[1 * 257 + j];
                float p2 = ps[2 * 257 + j], p3 = ps[3 * 257 + j];
                h0.x = fmaf(p0, xv.x, h0.x); h0.y = fmaf(p0, xv.y, h0.y);
                h0.z = fmaf(p0, xv.z, h0.z); h0.w = fmaf(p0, xv.w, h0.w);
                h1.x = fmaf(p1, xv.x, h1.x); h1.y = fmaf(p1, xv.y, h1.y);
                h1.z = fmaf(p1, xv.z, h1.z); h1.w = fmaf(p1, xv.w, h1.w);
                h2.x = fmaf(p2, xv.x, h2.x); h2.y = fmaf(p2, xv.y, h2.y);
                h2.z = fmaf(p2, xv.z, h2.z); h2.w = fmaf(p2, xv.w, h2.w);
                h3.x = fmaf(p3, xv.x, h3.x); h3.y = fmaf(p3, xv.y, h3.y);
                h3.z = fmaf(p3, xv.z, h3.z); h3.w = fmaf(p3, xv.w, h3.w);
            }
#pragma unroll
            for (int off = 16; off <= 32; off <<= 1) {
                h0.x += __shfl_xor(h0.x, off); h0.y += __shfl_xor(h0.y, off);
                h0.z += __shfl_xor(h0.z, off); h0.w += __shfl_xor(h0.w, off);
                h1.x += __shfl_xor(h1.x, off); h1.y += __shfl_xor(h1.y, off);
                h1.z += __shfl_xor(h1.z, off); h1.w += __shfl_xor(h1.w, off);
                h2.x += __shfl_xor(h2.x, off); h2.y += __shfl_xor(h2.y, off);
                h2.z += __shfl_xor(h2.z, off); h2.w += __shfl_xor(h2.w, off);
                h3.x += __shfl_xor(h3.x, off); h3.y += __shfl_xor(h3.y, off);
                h3.z += __shfl_xor(h3.z, off); h3.w += __shfl_xor(h3.w, off);
            }
            if (lane < 16) {
                hpart[wave][0][lane] = h0; hpart[wave][1][lane] = h1;
                hpart[wave][2][lane] = h2; hpart[wave][3][lane] = h3;
            }
        }
        __syncthreads();
        if (t < 64) {
            const int i = t >> 4, f4 = t & 15;
            float4 A = hpart[0][i][f4], Bq = hpart[1][i][f4];
            float4 C = hpart[2][i][f4], D = hpart[3][i][f4];
            float4 hv;
            hv.x = A.x + Bq.x + C.x + D.x; hv.y = A.y + Bq.y + C.y + D.y;
            hv.z = A.z + Bq.z + C.z + D.z; hv.w = A.w + Bq.w + C.w + D.w;
            hv.x = 1.f / (1.f + __expf(-hv.x)); hv.y = 1.f / (1.f + __expf(-hv.y));
            hv.z = 1.f / (1.f + __expf(-hv.z)); hv.w = 1.f / (1.f + __expf(-hv.w));
            h4s[i][f4] = hv;
        }
        __syncthreads();

        // fc epilogue: thread = (i=wave, o=lane)
        {
            float acc = 0.f;
#pragma unroll
            for (int f4 = 0; f4 < 16; ++f4) {
                float4 hv = h4s[wave][f4];       // broadcast
                float4 wv = fcp[f4 * 64 + lane]; // coalesced
                acc = fmaf(hv.x, wv.x, acc); acc = fmaf(hv.y, wv.y, acc);
                acc = fmaf(hv.z, wv.z, acc); acc = fmaf(hv.w, wv.w, acc);
            }
            out[(b * K + i0 + wave) * F + lane] = acc + fc_b[lane];
        }
    }
}

extern "C" void kernel_launch(void* const* d_in, const int* in_sizes, int n_in,
                              void* d_out, int out_size, void* d_ws, size_t ws_size,
                              hipStream_t stream) {
    const float* x        = (const float*)d_in[0];
    const float* lin_w    = (const float*)d_in[1];
    const float* lin_b    = (const float*)d_in[2];
    const float* a        = (const float*)d_in[3];
    const float* att_bias = (const float*)d_in[4];
    const float* fc_w     = (const float*)d_in[5];
    const float* fc_b     = (const float*)d_in[6];
    float* out = (float*)d_out;

    float* u   = (float*)d_ws;                     // 262144 floats
    float* vT  = u + B * K * E;                    // 262144
    float* c   = vT + B * K * E;                   // 2048
    float* d   = c + B * K;                        // 2048
    float4* wq  = (float4*)(d + B * K);            // 4096 float4
    float4* fcp = wq + 32 * E;                     // 1024 float4

    void* args[] = {(void*)&x, (void*)&lin_w, (void*)&lin_b, (void*)&a,
                    (void*)&att_bias, (void*)&fc_w, (void*)&fc_b,
                    (void*)&u, (void*)&vT, (void*)&c, (void*)&d,
                    (void*)&wq, (void*)&fcp, (void*)&out};
    hipLaunchCooperativeKernel((void*)gat_fused, dim3(512), dim3(256), args, 0, stream);
}

// Round 5
// 29.086 us; speedup vs baseline: 4.8939x; 4.8939x over previous
//
#include <hip/hip_runtime.h>
#include <hip/hip_bf16.h>

#define ALPHA 0.2f
constexpr int B = 8, K = 256, F = 64, E = 128;   // E = 2*F

// ---------------------------------------------------------------------------
// Workspace floats:
//   u   [B*K][E]                                               262144
//   vT  float4-transposed v: f4-idx (b*32+e4)*K + k, comp e&3  262144
//   c   [B*K] = sum_e a_e*v, d [B*K] = sum_e a_e*u             2048 + 2048
//   wq  float4 [32][128] packed lin_w                          16384 fl
//   fcp float4 [16][64]  packed fc_w                           4096 fl
// ---------------------------------------------------------------------------

// k0: pack weights for coalesced access (20 blocks x 256)
__global__ __launch_bounds__(256) void gat_k0(
    const float* __restrict__ lin_w, const float* __restrict__ fc_w,
    float4* __restrict__ wq, float4* __restrict__ fcp)
{
    int idx = blockIdx.x * 256 + threadIdx.x;
    if (idx < 32 * E) {                       // lin_w -> wq
        int e = idx & (E - 1), f2 = idx >> 7;
        const float* r = lin_w + e * (2 * F) + 2 * f2;
        wq[f2 * E + e] = make_float4(r[0], r[1], r[F], r[F + 1]);
    } else {                                  // fc_w -> fcp
        int k = idx - 32 * E;
        int f4 = k >> 6, o = k & 63;
        const float* r = fc_w + o * F + f4 * 4;
        fcp[k] = make_float4(r[0], r[1], r[2], r[3]);
    }
}

// k1: 512 blocks x 256 threads; thread (e, rh) computes 2 rows -> 4 rows/block.
__global__ __launch_bounds__(256) void gat_k1(
    const float* __restrict__ x, const float4* __restrict__ wq,
    const float* __restrict__ lin_b, const float* __restrict__ a,
    float* __restrict__ u, float* __restrict__ vT,
    float* __restrict__ c, float* __restrict__ d)
{
    const int t = threadIdx.x;
    const int wave = t >> 6, lane = t & 63;
    const int row0 = blockIdx.x * 4;
    const int e = t & 127, rh = t >> 7;
    const int b = row0 >> 8;

    __shared__ float xs[4 * F];
    __shared__ float redA[4][4];

    xs[t] = x[row0 * F + t];
    __syncthreads();

    const float* xr0 = &xs[(rh * 2) * F];
    const float* xr1 = &xs[(rh * 2 + 1) * F];
    float a10 = 0.f, a11 = 0.f, a20 = 0.f, a21 = 0.f;
#pragma unroll
    for (int f2 = 0; f2 < 32; ++f2) {
        float4 w = wq[f2 * E + e];           // coalesced 16B/lane, L1-shared
        float x0 = xr0[2 * f2], x1 = xr0[2 * f2 + 1];
        float y0 = xr1[2 * f2], y1 = xr1[2 * f2 + 1];
        a10 = fmaf(w.x, x0, fmaf(w.y, x1, a10));
        a20 = fmaf(w.z, x0, fmaf(w.w, x1, a20));
        a11 = fmaf(w.x, y0, fmaf(w.y, y1, a11));
        a21 = fmaf(w.z, y0, fmaf(w.w, y1, a21));
    }
    const float bb = lin_b[e], av = a[e];
    const float u0 = a10 + bb, u1 = a11 + bb;
    const int r0 = row0 + rh * 2;
    u[r0 * E + e] = u0;
    u[(r0 + 1) * E + e] = u1;
    const int kk = r0 & (K - 1);
    float* vbase = vT + ((b * 32 + (e >> 2)) * K) * 4 + (e & 3);
    vbase[kk * 4] = a20;
    vbase[(kk + 1) * 4] = a21;

    float vals[4] = {av * a20, av * u0, av * a21, av * u1};  // c0,d0,c1,d1
#pragma unroll
    for (int off = 32; off; off >>= 1) {
#pragma unroll
        for (int q = 0; q < 4; ++q) vals[q] += __shfl_xor(vals[q], off);
    }
    if (lane == 0) {
        redA[wave][0] = vals[0]; redA[wave][1] = vals[1];
        redA[wave][2] = vals[2]; redA[wave][3] = vals[3];
    }
    __syncthreads();
    if (t < 8) {
        int r = t >> 1, w = t & 1;           // row 0..3, 0=c 1=d
        int wp = (r >> 1) * 2, q = (r & 1) * 2 + w;
        float val = redA[wp][q] + redA[wp + 1][q];
        if (w == 0) c[row0 + r] = val; else d[row0 + r] = val;
    }
}

// k2: 512 blocks x 256 threads; block = (b, 4 i-rows); thread t = j for e-loop.
__global__ __launch_bounds__(256) void gat_k2(
    const float* __restrict__ x, const float* __restrict__ a,
    const float* __restrict__ att_bias, const float4* __restrict__ fcp,
    const float* __restrict__ fc_b, const float* __restrict__ u,
    const float4* __restrict__ vT4, const float* __restrict__ c,
    const float* __restrict__ d, float* __restrict__ out)
{
    const int blk = blockIdx.x;
    const int b = blk >> 6;
    const int i0 = (blk & 63) * 4;
    const int t = threadIdx.x;               // j
    const int wave = t >> 6, lane = t & 63;

    __shared__ float4 us4[4 * 32];           // u rows i0..i0+3
    __shared__ float aas[E];                 // 0.4 * a
    __shared__ float ps[4 * 257];
    __shared__ float4 hpart[4][4][16];
    __shared__ float4 h4s[4][16];
    __shared__ float redm[4][4], reds[4][4];

    // ---- preamble ----
    if (t < 128) {
        const float4* usrc = (const float4*)(u + (size_t)(b * K + i0) * E);
        us4[t] = usrc[t];
        aas[t] = 0.4f * a[t];
    }
    const float cj = c[b * K + t];
    const float d0 = d[b * K + i0],     d1 = d[b * K + i0 + 1];
    const float d2 = d[b * K + i0 + 2], d3 = d[b * K + i0 + 3];
    const float ab0 = att_bias[(i0 + 0) * K + t];
    const float ab1 = att_bias[(i0 + 1) * K + t];
    const float ab2 = att_bias[(i0 + 2) * K + t];
    const float ab3 = att_bias[(i0 + 3) * K + t];
    __syncthreads();

    // ---- e-loop: ej[i] = sum_e (0.4 a_e)|u_ie + v_je|, 1 global load/iter ----
    const float4* v4 = vT4 + (size_t)b * 32 * K + t;
    const float* us = (const float*)us4;
    float ej0 = 0.f, ej1 = 0.f, ej2 = 0.f, ej3 = 0.f;
#pragma unroll 8
    for (int e4 = 0; e4 < 32; ++e4) {
        float4 v  = v4[e4 * K];
        float4 aa = *(const float4*)&aas[e4 * 4];
        float4 u0 = *(const float4*)&us[0 * E + e4 * 4];
        float4 u1 = *(const float4*)&us[1 * E + e4 * 4];
        float4 u2 = *(const float4*)&us[2 * E + e4 * 4];
        float4 u3 = *(const float4*)&us[3 * E + e4 * 4];
        ej0 = fmaf(aa.x, fabsf(u0.x + v.x), ej0); ej0 = fmaf(aa.y, fabsf(u0.y + v.y), ej0);
        ej0 = fmaf(aa.z, fabsf(u0.z + v.z), ej0); ej0 = fmaf(aa.w, fabsf(u0.w + v.w), ej0);
        ej1 = fmaf(aa.x, fabsf(u1.x + v.x), ej1); ej1 = fmaf(aa.y, fabsf(u1.y + v.y), ej1);
        ej1 = fmaf(aa.z, fabsf(u1.z + v.z), ej1); ej1 = fmaf(aa.w, fabsf(u1.w + v.w), ej1);
        ej2 = fmaf(aa.x, fabsf(u2.x + v.x), ej2); ej2 = fmaf(aa.y, fabsf(u2.y + v.y), ej2);
        ej2 = fmaf(aa.z, fabsf(u2.z + v.z), ej2); ej2 = fmaf(aa.w, fabsf(u2.w + v.w), ej2);
        ej3 = fmaf(aa.x, fabsf(u3.x + v.x), ej3); ej3 = fmaf(aa.y, fabsf(u3.y + v.y), ej3);
        ej3 = fmaf(aa.z, fabsf(u3.z + v.z), ej3); ej3 = fmaf(aa.w, fabsf(u3.w + v.w), ej3);
    }
    float e0 = fmaf(0.6f, d0 + cj, ej0) + ab0;
    float e1 = fmaf(0.6f, d1 + cj, ej1) + ab1;
    float e2 = fmaf(0.6f, d2 + cj, ej2) + ab2;
    float e3 = fmaf(0.6f, d3 + cj, ej3) + ab3;

    // ---- softmax over j (4 rows) ----
    float m0 = e0, m1 = e1, m2 = e2, m3 = e3;
#pragma unroll
    for (int off = 32; off; off >>= 1) {
        m0 = fmaxf(m0, __shfl_xor(m0, off)); m1 = fmaxf(m1, __shfl_xor(m1, off));
        m2 = fmaxf(m2, __shfl_xor(m2, off)); m3 = fmaxf(m3, __shfl_xor(m3, off));
    }
    if (lane == 0) { redm[wave][0] = m0; redm[wave][1] = m1; redm[wave][2] = m2; redm[wave][3] = m3; }
    __syncthreads();
    m0 = fmaxf(fmaxf(redm[0][0], redm[1][0]), fmaxf(redm[2][0], redm[3][0]));
    m1 = fmaxf(fmaxf(redm[0][1], redm[1][1]), fmaxf(redm[2][1], redm[3][1]));
    m2 = fmaxf(fmaxf(redm[0][2], redm[1][2]), fmaxf(redm[2][2], redm[3][2]));
    m3 = fmaxf(fmaxf(redm[0][3], redm[1][3]), fmaxf(redm[2][3], redm[3][3]));
    float x0 = __expf(e0 - m0), x1 = __expf(e1 - m1), x2 = __expf(e2 - m2), x3 = __expf(e3 - m3);
    float s0 = x0, s1 = x1, s2 = x2, s3 = x3;
#pragma unroll
    for (int off = 32; off; off >>= 1) {
        s0 += __shfl_xor(s0, off); s1 += __shfl_xor(s1, off);
        s2 += __shfl_xor(s2, off); s3 += __shfl_xor(s3, off);
    }
    if (lane == 0) { reds[wave][0] = s0; reds[wave][1] = s1; reds[wave][2] = s2; reds[wave][3] = s3; }
    __syncthreads();
    s0 = reds[0][0] + reds[1][0] + reds[2][0] + reds[3][0];
    s1 = reds[0][1] + reds[1][1] + reds[2][1] + reds[3][1];
    s2 = reds[0][2] + reds[1][2] + reds[2][2] + reds[3][2];
    s3 = reds[0][3] + reds[1][3] + reds[2][3] + reds[3][3];
    ps[0 * 257 + t] = x0 / s0;
    ps[1 * 257 + t] = x1 / s1;
    ps[2 * 257 + t] = x2 / s2;
    ps[3 * 257 + t] = x3 / s3;
    __syncthreads();

    // ---- h-loop: thread = (jg, fq); each x float4 loaded ONCE, feeds 4 rows ----
    {
        const int jg = t >> 4, fq = t & 15;
        const float4* xb4 = (const float4*)x + (size_t)b * K * 16 + fq;
        float4 h0 = make_float4(0,0,0,0), h1 = h0, h2 = h0, h3 = h0;
#pragma unroll 4
        for (int jj = 0; jj < 16; ++jj) {
            int j = jg * 16 + jj;
            float4 xv = xb4[(size_t)j * 16];
            float p0 = ps[0 * 257 + j], p1 = ps[1 * 257 + j];
            float p2 = ps[2 * 257 + j], p3 = ps[3 * 257 + j];
            h0.x = fmaf(p0, xv.x, h0.x); h0.y = fmaf(p0, xv.y, h0.y);
            h0.z = fmaf(p0, xv.z, h0.z); h0.w = fmaf(p0, xv.w, h0.w);
            h1.x = fmaf(p1, xv.x, h1.x); h1.y = fmaf(p1, xv.y, h1.y);
            h1.z = fmaf(p1, xv.z, h1.z); h1.w = fmaf(p1, xv.w, h1.w);
            h2.x = fmaf(p2, xv.x, h2.x); h2.y = fmaf(p2, xv.y, h2.y);
            h2.z = fmaf(p2, xv.z, h2.z); h2.w = fmaf(p2, xv.w, h2.w);
            h3.x = fmaf(p3, xv.x, h3.x); h3.y = fmaf(p3, xv.y, h3.y);
            h3.z = fmaf(p3, xv.z, h3.z); h3.w = fmaf(p3, xv.w, h3.w);
        }
#pragma unroll
        for (int off = 16; off <= 32; off <<= 1) {
            h0.x += __shfl_xor(h0.x, off); h0.y += __shfl_xor(h0.y, off);
            h0.z += __shfl_xor(h0.z, off); h0.w += __shfl_xor(h0.w, off);
            h1.x += __shfl_xor(h1.x, off); h1.y += __shfl_xor(h1.y, off);
            h1.z += __shfl_xor(h1.z, off); h1.w += __shfl_xor(h1.w, off);
            h2.x += __shfl_xor(h2.x, off); h2.y += __shfl_xor(h2.y, off);
            h2.z += __shfl_xor(h2.z, off); h2.w += __shfl_xor(h2.w, off);
            h3.x += __shfl_xor(h3.x, off); h3.y += __shfl_xor(h3.y, off);
            h3.z += __shfl_xor(h3.z, off); h3.w += __shfl_xor(h3.w, off);
        }
        if (lane < 16) {
            hpart[wave][0][lane] = h0; hpart[wave][1][lane] = h1;
            hpart[wave][2][lane] = h2; hpart[wave][3][lane] = h3;
        }
    }
    __syncthreads();
    if (t < 64) {
        const int i = t >> 4, f4 = t & 15;
        float4 A = hpart[0][i][f4], Bq = hpart[1][i][f4];
        float4 C = hpart[2][i][f4], D = hpart[3][i][f4];
        float4 hv;
        hv.x = A.x + Bq.x + C.x + D.x; hv.y = A.y + Bq.y + C.y + D.y;
        hv.z = A.z + Bq.z + C.z + D.z; hv.w = A.w + Bq.w + C.w + D.w;
        hv.x = 1.f / (1.f + __expf(-hv.x)); hv.y = 1.f / (1.f + __expf(-hv.y));
        hv.z = 1.f / (1.f + __expf(-hv.z)); hv.w = 1.f / (1.f + __expf(-hv.w));
        h4s[i][f4] = hv;
    }
    __syncthreads();

    // ---- fc epilogue: thread = (i=wave, o=lane) ----
    {
        float acc = 0.f;
#pragma unroll
        for (int f4 = 0; f4 < 16; ++f4) {
            float4 hv = h4s[wave][f4];       // broadcast
            float4 wv = fcp[f4 * 64 + lane]; // coalesced
            acc = fmaf(hv.x, wv.x, acc); acc = fmaf(hv.y, wv.y, acc);
            acc = fmaf(hv.z, wv.z, acc); acc = fmaf(hv.w, wv.w, acc);
        }
        out[(b * K + i0 + wave) * F + lane] = acc + fc_b[lane];
    }
}

extern "C" void kernel_launch(void* const* d_in, const int* in_sizes, int n_in,
                              void* d_out, int out_size, void* d_ws, size_t ws_size,
                              hipStream_t stream) {
    const float* x        = (const float*)d_in[0];
    const float* lin_w    = (const float*)d_in[1];
    const float* lin_b    = (const float*)d_in[2];
    const float* a        = (const float*)d_in[3];
    const float* att_bias = (const float*)d_in[4];
    const float* fc_w     = (const float*)d_in[5];
    const float* fc_b     = (const float*)d_in[6];
    float* out = (float*)d_out;

    float* u   = (float*)d_ws;                     // 262144 floats
    float* vT  = u + B * K * E;                    // 262144
    float* c   = vT + B * K * E;                   // 2048
    float* d   = c + B * K;                        // 2048
    float4* wq  = (float4*)(d + B * K);            // 4096 float4
    float4* fcp = wq + 32 * E;                     // 1024 float4

    gat_k0<<<20, 256, 0, stream>>>(lin_w, fc_w, wq, fcp);
    gat_k1<<<B * K / 4, 256, 0, stream>>>(x, wq, lin_b, a, u, vT, c, d);
    gat_k2<<<B * K / 4, 256, 0, stream>>>(x, a, att_bias, fcp, fc_b, u,
                                          (const float4*)vT, c, d, out);
}